// Round 5
// baseline (580.699 us; speedup 1.0000x reference)
//
#include <hip/hip_runtime.h>

#define N_ 32
#define C_ 64
#define T_ 256
#define V_ 25
#define O_ 192
#define S_ 3
#define R_ 8
#define VV (V_*V_)      // 625
#define TV (T_*V_)      // 6400

typedef unsigned short u16;
typedef __attribute__((ext_vector_type(4))) u16 u16x4;
typedef __attribute__((ext_vector_type(8))) u16 u16x8;
typedef __attribute__((ext_vector_type(8))) __bf16 bf16x8;
typedef __attribute__((ext_vector_type(4))) float f32x4;

// ---- workspace layout ----
// u16 region:
#define WS_A2F_U 0                                   // N*O*6*64*8 = 18,874,368
#define WS_XBP_U (18874368)                          // N*256*32*64 = 16,777,216
#define WS_XD_U  (18874368 + 16777216)               // N*O*TV = 39,321,600
// float region (after 74,973,184 u16 = 149,946,368 B):
#define WS_XM_F   (37486592)                         // N*C*V = 51,200
#define WS_RS_F   (37486592 + 51200)                 // N*O*V = 153,600
#define WS_STAT_F (37486592 + 51200 + 153600)        // 4*O
#define WS_COEF_F (37486592 + 51200 + 153600 + 768)  // 4*O

__device__ __forceinline__ u16 f2b(float f) {
    return __builtin_bit_cast(u16, (__bf16)f);
}
__device__ __forceinline__ float b2f(u16 u) {
    return __builtin_bit_cast(float, ((unsigned)u) << 16);
}
__device__ __forceinline__ f32x4 mfma16(bf16x8 a, bf16x8 b, f32x4 c) {
    return __builtin_amdgcn_mfma_f32_16x16x32_bf16(a, b, c, 0, 0, 0);
}
__device__ __forceinline__ bf16x8 joinfrag(u16x4 lo, u16x4 hi) {
    return __builtin_bit_cast(bf16x8,
        __builtin_shufflevector(lo, hi, 0, 1, 2, 3, 4, 5, 6, 7));
}

// ---------------- K0: x[n,c,t,v] fp32 -> xbp[n][t][32 pad][64 c] bf16 ----------------
// grid N*128, each block: 2 t rows (50 real tv -> 64 padded rows)
__global__ void k0_xbp(const float* __restrict__ x, u16* __restrict__ xbp) {
    __shared__ float tile[64][52];
    int bid = blockIdx.x;
    int n = bid >> 7, tb = bid & 127;
    int t0 = tb * 2;
    int tid = threadIdx.x;
    const float2* xp = (const float2*)(x + (size_t)n * C_ * TV + t0 * 25);
    for (int p = tid; p < 1600; p += 256) {
        int c = p / 25, q = p % 25;
        float2 f2 = xp[(size_t)c * 3200 + q];
        tile[c][q * 2] = f2.x;
        tile[c][q * 2 + 1] = f2.y;
    }
    __syncthreads();
    for (int p = tid; p < 1024; p += 256) {
        int row = p >> 4, c4 = (p & 15) * 4;
        int t = row >> 5, v = row & 31;
        u16x4 w;
        #pragma unroll
        for (int i = 0; i < 4; ++i)
            w[i] = (v < 25) ? f2b(tile[c4 + i][t * 25 + v]) : (u16)0;
        *(u16x4*)&xbp[((size_t)n * 8192 + (size_t)(t0 + t) * 32 + v) * 64 + c4] = w;
    }
}

// ---------------- K1: xm[n,c,v] = mean_t x[n,c,t,v] ----------------
__global__ void k1_xm(const float* __restrict__ x, float* __restrict__ xm_out) {
    __shared__ float ps[256];
    int nc = blockIdx.x;
    int tid = threadIdx.x;
    const float* xp = x + (size_t)nc * TV;
    float acc = 0.f;
    if (tid < 250) {
        int tg = tid / 25, v = tid % 25;
        for (int j = 0; j < 26; ++j) {
            int t = tg + 10 * j;
            if (t < T_) acc += xp[t * V_ + v];
        }
    }
    ps[tid] = acc;
    __syncthreads();
    if (tid < V_) {
        float s = 0.f;
        for (int tg = 0; tg < 10; ++tg) s += ps[tg * 25 + tid];
        xm_out[(size_t)nc * V_ + tid] = s * (1.f / T_);
    }
}

// ---------------- K2: build A2F (frag-swizzled A_at, bf16) + rs_tot bias ----------------
// grid: N*S*8 ; each block does 24 o's
__global__ void k2_a2f(const float* __restrict__ spd, const float* __restrict__ A3,
                       const float* __restrict__ A6,
                       const float* __restrict__ w1, const float* __restrict__ b1,
                       const float* __restrict__ w2, const float* __restrict__ b2,
                       const float* __restrict__ w4, const float* __restrict__ b4,
                       const float* __restrict__ b3,
                       const float* __restrict__ alpha, const float* __restrict__ beta,
                       const float* __restrict__ gamma,
                       u16* __restrict__ a2f, const float* __restrict__ xmbuf,
                       float* __restrict__ rs_tot) {
    __shared__ float xm[C_ * V_];
    __shared__ float x1s[R_ * V_], x2s[R_ * V_];
    __shared__ float dm[R_ * VV];
    __shared__ float a3s[VV], sps[VV], a6s[6 * VV];
    __shared__ float aat[2 * VV];
    __shared__ float w4s[2][R_];
    __shared__ float b4s[2];
    int bid = blockIdx.x;
    int n = bid / 24;
    int rem = bid % 24;
    int s = rem / 8, og = rem % 8;
    int tid = threadIdx.x;
    const float* xmg = xmbuf + (size_t)n * C_ * V_;
    for (int p = tid; p < C_ * V_; p += 256) xm[p] = xmg[p];
    for (int p = tid; p < VV; p += 256) { a3s[p] = A3[s * VV + p]; sps[p] = spd[p]; }
    for (int p = tid; p < 6 * VV; p += 256) a6s[p] = A6[p];
    __syncthreads();
    if (tid < R_ * V_) {
        int r = tid / V_, v = tid % V_;
        float acc1 = b1[s * R_ + r], acc2 = b2[s * R_ + r];
        for (int c = 0; c < C_; ++c) {
            float xv = xm[c * V_ + v];
            acc1 += xv * w1[(s * R_ + r) * C_ + c];
            acc2 += xv * w2[(s * R_ + r) * C_ + c];
        }
        x1s[tid] = acc1; x2s[tid] = acc2;
    }
    __syncthreads();
    for (int p = tid; p < R_ * VV; p += 256) {
        int r = p / VV, uv = p % VV, u = uv / V_, v = uv % V_;
        dm[p] = tanhf(x1s[r * V_ + u] - x2s[r * V_ + v]);
    }
    __syncthreads();
    float al = alpha[0], be = beta[0], ga = gamma[0];
    for (int op = 0; op < 12; ++op) {
        int o0 = og * 24 + op * 2;
        if (tid < 16) w4s[tid >> 3][tid & 7] =
            w4[((size_t)(s * O_ + o0 + (tid >> 3))) * R_ + (tid & 7)];
        if (tid < 2) b4s[tid] = b4[s * O_ + o0 + tid];
        __syncthreads();
        for (int p = tid; p < 2 * VV; p += 256) {
            int oo = p / VV, pp = p % VV;
            float acc = b4s[oo];
            #pragma unroll
            for (int r = 0; r < R_; ++r) acc += dm[r * VV + pp] * w4s[oo][r];
            int o = o0 + oo;
            aat[p] = al * acc + a3s[pp] + be * a6s[(o % 6) * VV + pp] + ga * sps[pp];
        }
        __syncthreads();
        if (tid < 2 * V_) {
            int oo = tid / V_, u = tid % V_;
            float rs = 0.f;
            for (int v = 0; v < V_; ++v) rs += aat[oo * VV + u * V_ + v];
            atomicAdd(&rs_tot[((size_t)(n * O_ + o0 + oo)) * V_ + u],
                      b3[s * O_ + o0 + oo] * rs);
        }
        {
            int oo = tid >> 7, l2 = tid & 127, cu = l2 >> 6, l = l2 & 63;
            int u = cu * 16 + (l & 15);
            u16x8 w;
            #pragma unroll
            for (int j = 0; j < 8; ++j) {
                int v = ((j >> 2) << 4) + ((l >> 4) << 2) + (j & 3);
                float val = 0.f;
                if (u < V_ && v < V_) val = aat[oo * VV + u * V_ + v];
                w[j] = f2b(val);
            }
            size_t idx = ((((size_t)(n * O_ + o0 + oo)) * S_ + s) * 2 + cu) * 64 + l;
            ((u16x8*)a2f)[idx] = w;
        }
        __syncthreads();
    }
}

// ---------------- K3: fused MFMA GEMM1+GEMM2 + down + stats ----------------
// grid N*24*2 = 1536 (6/CU). OB=8 o, t-half per block, 8 chunks of 16 t.
// x3L: [8 o][3 s][16 t][32 v] bf16, XOR-swizzled, single buffer 25.7 KB.
#define OSTR_B 3216          // o col stride bytes (= 3*1040 + 96 pad; /4 % 32 == 4)
#define SSTR_B 1040          // s stride bytes (/4 % 32 == 4)

__global__ __launch_bounds__(256, 5)
void k3_main(const u16* __restrict__ xbp,
             const float* __restrict__ w3, const float* __restrict__ dw,
             const float* __restrict__ db,
             const u16* __restrict__ a2f, const float* __restrict__ rs_tot,
             float* __restrict__ yout, u16* __restrict__ xdws,
             float* __restrict__ stats) {
    __shared__ char x3Lb[8 * OSTR_B];   // 25,728 B
    int orig = blockIdx.x;
    int bid = (orig & 7) * 192 + (orig >> 3);   // same-n blocks -> same XCD
    int n = bid / 48;
    int rem = bid % 48;
    int o0 = (rem >> 1) * 8;
    int th = rem & 1;
    int tid = threadIdx.x, wid = tid >> 6, lane = tid & 63;
    int lr = lane & 15, lg = lane >> 4;
    int colt = wid & 1;
    int rt0 = (wid >> 1) * 16;

    // GEMM1 B-frags: colt0 cols = (s0,o0..7)|(s1,o0..7); colt1 = (s2,o0..7)|(down,o0..7)
    const float* wsrc = (colt == 0)
        ? w3 + ((size_t)((lr >> 3) * O_ + o0 + (lr & 7))) * C_
        : ((lr < 8) ? w3 + ((size_t)(2 * O_ + o0 + lr)) * C_
                    : dw + ((size_t)(o0 + lr - 8)) * C_);
    bf16x8 bw[2];
    #pragma unroll
    for (int ks = 0; ks < 2; ++ks) {
        u16x8 tmp;
        #pragma unroll
        for (int j = 0; j < 8; ++j) {
            int c = ks * 32 + (lg << 2) + (j & 3) + ((j >> 2) << 4);
            tmp[j] = f2b(wsrc[c]);
        }
        bw[ks] = __builtin_bit_cast(bf16x8, tmp);
    }
    float dbv = (colt == 1 && lr >= 8) ? db[o0 + lr - 8] : 0.f;

    // per-lane LDS write base (colt0 all lanes; colt1 only lr<8)
    int wo = (colt == 0) ? (lr & 7) : lr;
    int wsb = (colt == 0) ? (lr >> 3) : 2;
    int colbyte = wo * OSTR_B + wsb * SSTR_B;

    // hoisted GEMM2 B-frags + bias: wave covers o = o0 + wid*2 + {0,1}
    const bf16x8* a2v = (const bf16x8*)a2f;
    bf16x8 Bh[2][6];
    float rsb0[2], rsb1[2];
    #pragma unroll
    for (int oi = 0; oi < 2; ++oi) {
        int o = o0 + (wid << 1) + oi;
        const bf16x8* bp = a2v + ((size_t)(n * O_ + o)) * 6 * 64 + lane;
        #pragma unroll
        for (int q = 0; q < 6; ++q) Bh[oi][q] = bp[(size_t)q * 64];
        const float* rsp = rs_tot + ((size_t)(n * O_ + o)) * V_;
        rsb0[oi] = rsp[lr];
        rsb1[oi] = (lr < 9) ? rsp[16 + lr] : 0.f;
    }

    float sy1[2] = {0, 0}, sy2[2] = {0, 0};
    float sd1 = 0.f, sd2 = 0.f;
    const u16* xbn = xbp + (size_t)n * 8192 * 64;
    // GEMM2 read bases (swizzled, loop-invariant)
    int qlo = ((lr << 6) | (lg << 3)) ^ ((lr & 7) << 4);
    int qhi = qlo ^ 32;

    for (int ch = 0; ch < 8; ++ch) {
        int t0 = th * 128 + ch * 16;
        const u16* xrow = xbn + (size_t)t0 * 32 * 64;
        // ---- GEMM1: A from global (linear padded rows), out -> swizzled LDS
        for (int rt = rt0; rt < rt0 + 16; ++rt) {
            const u16* ap = xrow + (size_t)(rt * 16 + lr) * 64 + (lg << 2);
            u16x4 a0 = *(const u16x4*)ap;
            u16x4 a1 = *(const u16x4*)(ap + 16);
            u16x4 a2 = *(const u16x4*)(ap + 32);
            u16x4 a3 = *(const u16x4*)(ap + 48);
            f32x4 acc = {0.f, 0.f, 0.f, 0.f};
            acc = mfma16(joinfrag(a0, a1), bw[0], acc);
            acc = mfma16(joinfrag(a2, a3), bw[1], acc);
            int tvb = rt * 16 + (lg << 2);
            int t = tvb >> 5, v = tvb & 31;
            if (colt == 0 || lr < 8) {
                int swz = ((t << 6) | (v << 1)) ^ ((t & 7) << 4);
                u16x4 w;
                #pragma unroll
                for (int reg = 0; reg < 4; ++reg) w[reg] = f2b(acc[reg]);
                *(u16x4*)(x3Lb + colbyte + swz) = w;
            } else {
                size_t xdb = ((size_t)(n * O_ + o0 + lr - 8)) * TV + (size_t)(t0 + t) * V_;
                #pragma unroll
                for (int reg = 0; reg < 4; ++reg) {
                    int vv = v + reg;
                    if (vv < 25) {
                        float val = acc[reg] + dbv;
                        xdws[xdb + vv] = f2b(val);
                        sd1 += val; sd2 += val * val;
                    }
                }
            }
        }
        __syncthreads();
        // ---- GEMM2: y[t,u] = sum_{s,v} X3[t,(s,v)] * A2[(s,v),u]
        #pragma unroll
        for (int oi = 0; oi < 2; ++oi) {
            int ol = (wid << 1) + oi;
            int o = o0 + ol;
            const char* p1 = x3Lb + ol * OSTR_B + qlo;
            const char* p2 = x3Lb + ol * OSTR_B + qhi;
            f32x4 acc0 = {0, 0, 0, 0}, acc1 = {0, 0, 0, 0};
            #pragma unroll
            for (int s = 0; s < 3; ++s) {
                u16x4 lo = *(const u16x4*)(p1 + s * SSTR_B);
                u16x4 hi = *(const u16x4*)(p2 + s * SSTR_B);
                bf16x8 A = joinfrag(lo, hi);
                acc0 = mfma16(A, Bh[oi][s * 2 + 0], acc0);
                acc1 = mfma16(A, Bh[oi][s * 2 + 1], acc1);
            }
            size_t yb = ((size_t)(n * O_ + o) * T_ + t0 + (lg << 2)) * V_;
            #pragma unroll
            for (int reg = 0; reg < 4; ++reg) {
                float v0 = acc0[reg] + rsb0[oi];
                yout[yb + (size_t)reg * V_ + lr] = v0;
                sy1[oi] += v0; sy2[oi] += v0 * v0;
                if (lr < 9) {
                    float v1 = acc1[reg] + rsb1[oi];
                    yout[yb + (size_t)reg * V_ + 16 + lr] = v1;
                    sy1[oi] += v1; sy2[oi] += v1 * v1;
                }
            }
        }
        __syncthreads();
    }
    // stats -> global atomics
    #pragma unroll
    for (int oi = 0; oi < 2; ++oi) {
        float v1 = sy1[oi], v2 = sy2[oi];
        #pragma unroll
        for (int m = 1; m < 64; m <<= 1) {
            v1 += __shfl_xor(v1, m);
            v2 += __shfl_xor(v2, m);
        }
        if (lane == 0) {
            atomicAdd(&stats[0 * O_ + o0 + (wid << 1) + oi], v1);
            atomicAdd(&stats[1 * O_ + o0 + (wid << 1) + oi], v2);
        }
    }
    if (colt == 1) {
        float v1 = sd1, v2 = sd2;
        v1 += __shfl_xor(v1, 16); v2 += __shfl_xor(v2, 16);
        v1 += __shfl_xor(v1, 32); v2 += __shfl_xor(v2, 32);
        if (lane >= 8 && lane < 16) {
            atomicAdd(&stats[2 * O_ + o0 + lane - 8], v1);
            atomicAdd(&stats[3 * O_ + o0 + lane - 8], v2);
        }
    }
}

// ---------------- K4: BN coefficients ----------------
__global__ void k4_coef(const float* __restrict__ bn_w, const float* __restrict__ bn_b,
                        const float* __restrict__ dbn_w, const float* __restrict__ dbn_b,
                        const float* __restrict__ stats, float* __restrict__ coef) {
    int o = threadIdx.x;
    if (o >= O_) return;
    float inv = 1.f / (float)(N_ * T_ * V_);
    float mu_y = stats[o] * inv;
    float var_y = stats[O_ + o] * inv - mu_y * mu_y;
    float ay = bn_w[o] * rsqrtf(var_y + 1e-5f);
    float by = bn_b[o] - mu_y * ay;
    float mu_d = stats[2 * O_ + o] * inv;
    float var_d = stats[3 * O_ + o] * inv - mu_d * mu_d;
    float ad = dbn_w[o] * rsqrtf(var_d + 1e-5f);
    float bd = dbn_b[o] - mu_d * ad;
    coef[o] = ay; coef[O_ + o] = by; coef[2 * O_ + o] = ad; coef[3 * O_ + o] = bd;
}

// ---------------- K5: final BN+residual+relu (in-place on d_out) ----------------
__global__ void k5_final(float* __restrict__ out, const u16* __restrict__ xd,
                         const float* __restrict__ cf) {
    size_t total = (size_t)N_ * O_ * TV / 8;
    for (size_t i = blockIdx.x * (size_t)blockDim.x + threadIdx.x; i < total;
         i += (size_t)gridDim.x * blockDim.x) {
        int o = (int)((i / 800) % O_);
        float ay = cf[o], by = cf[O_ + o], ad = cf[2 * O_ + o], bd = cf[3 * O_ + o];
        float4 y0 = ((float4*)out)[2 * i];
        float4 y1 = ((float4*)out)[2 * i + 1];
        u16x8 dv = ((const u16x8*)xd)[i];
        float4 r0, r1;
        r0.x = fmaxf(ay * y0.x + by + ad * b2f(dv[0]) + bd, 0.f);
        r0.y = fmaxf(ay * y0.y + by + ad * b2f(dv[1]) + bd, 0.f);
        r0.z = fmaxf(ay * y0.z + by + ad * b2f(dv[2]) + bd, 0.f);
        r0.w = fmaxf(ay * y0.w + by + ad * b2f(dv[3]) + bd, 0.f);
        r1.x = fmaxf(ay * y1.x + by + ad * b2f(dv[4]) + bd, 0.f);
        r1.y = fmaxf(ay * y1.y + by + ad * b2f(dv[5]) + bd, 0.f);
        r1.z = fmaxf(ay * y1.z + by + ad * b2f(dv[6]) + bd, 0.f);
        r1.w = fmaxf(ay * y1.w + by + ad * b2f(dv[7]) + bd, 0.f);
        ((float4*)out)[2 * i] = r0;
        ((float4*)out)[2 * i + 1] = r1;
    }
}

extern "C" void kernel_launch(void* const* d_in, const int* in_sizes, int n_in,
                              void* d_out, int out_size, void* d_ws, size_t ws_size,
                              hipStream_t stream) {
    const float* x     = (const float*)d_in[0];
    const float* spd   = (const float*)d_in[1];
    const float* A3    = (const float*)d_in[2];
    const float* A6    = (const float*)d_in[3];
    const float* w1    = (const float*)d_in[4];
    const float* b1    = (const float*)d_in[5];
    const float* w2    = (const float*)d_in[6];
    const float* b2    = (const float*)d_in[7];
    const float* w4    = (const float*)d_in[8];
    const float* b4    = (const float*)d_in[9];
    const float* w3    = (const float*)d_in[10];
    const float* b3    = (const float*)d_in[11];
    const float* alpha = (const float*)d_in[12];
    const float* beta  = (const float*)d_in[13];
    const float* gamma = (const float*)d_in[14];
    const float* bn_w  = (const float*)d_in[15];
    const float* bn_b  = (const float*)d_in[16];
    const float* dw    = (const float*)d_in[17];
    const float* db    = (const float*)d_in[18];
    const float* dbn_w = (const float*)d_in[19];
    const float* dbn_b = (const float*)d_in[20];
    float* out = (float*)d_out;
    u16*   wsu = (u16*)d_ws;
    float* wsf = (float*)d_ws;

    u16* a2f  = wsu + WS_A2F_U;
    u16* xbp  = wsu + WS_XBP_U;
    u16* xd   = wsu + WS_XD_U;
    float* xm    = wsf + WS_XM_F;
    float* rs    = wsf + WS_RS_F;
    float* stats = wsf + WS_STAT_F;
    float* coef  = wsf + WS_COEF_F;

    // zero rs_tot + stats (contiguous) — accumulated via atomics each call
    hipMemsetAsync(rs, 0, (N_ * O_ * V_ + 4 * O_) * sizeof(float), stream);

    k0_xbp<<<N_ * 128, 256, 0, stream>>>(x, xbp);
    k1_xm<<<N_ * C_, 256, 0, stream>>>(x, xm);
    k2_a2f<<<N_ * S_ * 8, 256, 0, stream>>>(spd, A3, A6, w1, b1, w2, b2, w4, b4, b3,
                                            alpha, beta, gamma, a2f, xm, rs);
    k3_main<<<N_ * 48, 256, 0, stream>>>(xbp, w3, dw, db, a2f, rs, out, xd, stats);
    k4_coef<<<1, 256, 0, stream>>>(bn_w, bn_b, dbn_w, dbn_b, stats, coef);
    k5_final<<<4096, 256, 0, stream>>>(out, xd, coef);
}

// Round 6
// 366.252 us; speedup vs baseline: 1.5855x; 1.5855x over previous
//
#include <hip/hip_runtime.h>

#define N_ 32
#define C_ 64
#define T_ 256
#define V_ 25
#define O_ 192
#define S_ 3
#define R_ 8
#define VV (V_*V_)      // 625
#define TV (T_*V_)      // 6400
#define RP 26           // padded v-rows per t
#define TRP (T_*RP)     // 6656 rows per n

typedef unsigned short u16;
typedef unsigned int u32;
typedef __attribute__((ext_vector_type(4))) u16 u16x4;
typedef __attribute__((ext_vector_type(8))) u16 u16x8;
typedef __attribute__((ext_vector_type(4))) u32 u32x4;
typedef __attribute__((ext_vector_type(8))) __bf16 bf16x8;
typedef __attribute__((ext_vector_type(4))) float f32x4;

// ---- workspace layout (u16 units) ----
#define WS_A2F_U 0                                   // N*O*6*64*8 = 18,874,368
#define WS_XQ_U  (18874368)                          // N*TRP*64 = 13,631,488
#define WS_XD_U  (18874368 + 13631488)               // N*O*TV = 39,321,600
// float region (after 71,827,456 u16):
#define WS_XM_F   (35913728)                         // N*C*V = 51,200
#define WS_RS_F   (35913728 + 51200)                 // N*O*V = 153,600
#define WS_STAT_F (35913728 + 51200 + 153600)        // 4*O
#define WS_COEF_F (35913728 + 51200 + 153600 + 768)  // 4*O

__device__ __forceinline__ u16 f2b(float f) {
    return __builtin_bit_cast(u16, (__bf16)f);
}
__device__ __forceinline__ float b2f(u16 u) {
    return __builtin_bit_cast(float, ((unsigned)u) << 16);
}
__device__ __forceinline__ f32x4 mfma16(bf16x8 a, bf16x8 b, f32x4 c) {
    return __builtin_amdgcn_mfma_f32_16x16x32_bf16(a, b, c, 0, 0, 0);
}

// ---------------- K0: x[n,c,t,v] fp32 -> xq[n][t*26+v][c' perm] bf16 ----------------
// c' = g*16 + j, where c_orig = (j>>2)*16 + g*4 + (j&3); v=25 row zeroed.
__global__ void k0_xq(const float* __restrict__ x, u16* __restrict__ xq) {
    __shared__ float tile[64][52];
    int bid = blockIdx.x;
    int n = bid >> 7, tb = bid & 127;
    int t0 = tb * 2;
    int tid = threadIdx.x;
    const float2* xp = (const float2*)(x + (size_t)n * C_ * TV + t0 * 25);
    for (int p = tid; p < 1600; p += 256) {
        int c = p / 25, q = p % 25;
        float2 f2 = xp[(size_t)c * 3200 + q];
        tile[c][q * 2] = f2.x;
        tile[c][q * 2 + 1] = f2.y;
    }
    __syncthreads();
    for (int p = tid; p < 832; p += 256) {
        int row = p >> 4, c4g = p & 15;          // row 0..51 = t*26+v (t local)
        int t = row >= RP, v = row - t * RP;
        u16x4 w;
        #pragma unroll
        for (int i = 0; i < 4; ++i) {
            int co = ((c4g & 3) << 4) + ((c4g >> 2) << 2) + i;
            w[i] = (v < 25) ? f2b(tile[co][t * 25 + v]) : (u16)0;
        }
        *(u16x4*)&xq[((size_t)n * TRP + tb * 52 + row) * 64 + c4g * 4] = w;
    }
}

// ---------------- K1: xm[n,c,v] = mean_t x[n,c,t,v] ----------------
__global__ void k1_xm(const float* __restrict__ x, float* __restrict__ xm_out) {
    __shared__ float ps[256];
    int nc = blockIdx.x;
    int tid = threadIdx.x;
    const float* xp = x + (size_t)nc * TV;
    float acc = 0.f;
    if (tid < 250) {
        int tg = tid / 25, v = tid % 25;
        for (int j = 0; j < 26; ++j) {
            int t = tg + 10 * j;
            if (t < T_) acc += xp[t * V_ + v];
        }
    }
    ps[tid] = acc;
    __syncthreads();
    if (tid < V_) {
        float s = 0.f;
        for (int tg = 0; tg < 10; ++tg) s += ps[tg * 25 + tid];
        xm_out[(size_t)nc * V_ + tid] = s * (1.f / T_);
    }
}

// ---------------- K2: build A2F (frag-swizzled A_at, bf16; v>=25 -> 0) + rs_tot ----------------
__global__ void k2_a2f(const float* __restrict__ spd, const float* __restrict__ A3,
                       const float* __restrict__ A6,
                       const float* __restrict__ w1, const float* __restrict__ b1,
                       const float* __restrict__ w2, const float* __restrict__ b2,
                       const float* __restrict__ w4, const float* __restrict__ b4,
                       const float* __restrict__ b3,
                       const float* __restrict__ alpha, const float* __restrict__ beta,
                       const float* __restrict__ gamma,
                       u16* __restrict__ a2f, const float* __restrict__ xmbuf,
                       float* __restrict__ rs_tot) {
    __shared__ float xm[C_ * V_];
    __shared__ float x1s[R_ * V_], x2s[R_ * V_];
    __shared__ float dm[R_ * VV];
    __shared__ float a3s[VV], sps[VV], a6s[6 * VV];
    __shared__ float aat[2 * VV];
    __shared__ float w4s[2][R_];
    __shared__ float b4s[2];
    int bid = blockIdx.x;
    int n = bid / 24;
    int rem = bid % 24;
    int s = rem / 8, og = rem % 8;
    int tid = threadIdx.x;
    const float* xmg = xmbuf + (size_t)n * C_ * V_;
    for (int p = tid; p < C_ * V_; p += 256) xm[p] = xmg[p];
    for (int p = tid; p < VV; p += 256) { a3s[p] = A3[s * VV + p]; sps[p] = spd[p]; }
    for (int p = tid; p < 6 * VV; p += 256) a6s[p] = A6[p];
    __syncthreads();
    if (tid < R_ * V_) {
        int r = tid / V_, v = tid % V_;
        float acc1 = b1[s * R_ + r], acc2 = b2[s * R_ + r];
        for (int c = 0; c < C_; ++c) {
            float xv = xm[c * V_ + v];
            acc1 += xv * w1[(s * R_ + r) * C_ + c];
            acc2 += xv * w2[(s * R_ + r) * C_ + c];
        }
        x1s[tid] = acc1; x2s[tid] = acc2;
    }
    __syncthreads();
    for (int p = tid; p < R_ * VV; p += 256) {
        int r = p / VV, uv = p % VV, u = uv / V_, v = uv % V_;
        dm[p] = tanhf(x1s[r * V_ + u] - x2s[r * V_ + v]);
    }
    __syncthreads();
    float al = alpha[0], be = beta[0], ga = gamma[0];
    for (int op = 0; op < 12; ++op) {
        int o0 = og * 24 + op * 2;
        if (tid < 16) w4s[tid >> 3][tid & 7] =
            w4[((size_t)(s * O_ + o0 + (tid >> 3))) * R_ + (tid & 7)];
        if (tid < 2) b4s[tid] = b4[s * O_ + o0 + tid];
        __syncthreads();
        for (int p = tid; p < 2 * VV; p += 256) {
            int oo = p / VV, pp = p % VV;
            float acc = b4s[oo];
            #pragma unroll
            for (int r = 0; r < R_; ++r) acc += dm[r * VV + pp] * w4s[oo][r];
            int o = o0 + oo;
            aat[p] = al * acc + a3s[pp] + be * a6s[(o % 6) * VV + pp] + ga * sps[pp];
        }
        __syncthreads();
        if (tid < 2 * V_) {
            int oo = tid / V_, u = tid % V_;
            float rs = 0.f;
            for (int v = 0; v < V_; ++v) rs += aat[oo * VV + u * V_ + v];
            atomicAdd(&rs_tot[((size_t)(n * O_ + o0 + oo)) * V_ + u],
                      b3[s * O_ + o0 + oo] * rs);
        }
        {
            int oo = tid >> 7, l2 = tid & 127, cu = l2 >> 6, l = l2 & 63;
            int u = cu * 16 + (l & 15);
            u16x8 w;
            #pragma unroll
            for (int j = 0; j < 8; ++j) {
                int v = ((j >> 2) << 4) + ((l >> 4) << 2) + (j & 3);
                float val = 0.f;
                if (u < V_ && v < V_) val = aat[oo * VV + u * V_ + v];
                w[j] = f2b(val);
            }
            size_t idx = ((((size_t)(n * O_ + o0 + oo)) * S_ + s) * 2 + cu) * 64 + l;
            ((u16x8*)a2f)[idx] = w;
        }
        __syncthreads();
    }
}

// ---------------- K3: fused MFMA GEMM1+GEMM2 + down + stats ----------------
// grid N*24 = 768 (3/CU). OB=8 o's, full t, 16 chunks of 16 t (416 rows each).
// x3L: [8 o][3 s][416 r] u16, linear in r; double-buffered.
#define OSTR_B 2504          // /4 = 626 ≡ 18 (mod 32): 16 distinct write banks
#define SSTR_B 832           // 416 rows * 2B
#define BUF_B  20096         // 8*2504 + 64 pad (overflow-read safety)

__global__ __launch_bounds__(256, 3)
void k3_main(const u16* __restrict__ xq,
             const float* __restrict__ w3, const float* __restrict__ dw,
             const float* __restrict__ db,
             const u16* __restrict__ a2f, const float* __restrict__ rs_tot,
             float* __restrict__ yout, u16* __restrict__ xdws,
             float* __restrict__ stats) {
    __shared__ char x3Lb[2 * BUF_B];   // 40,192 B
    int orig = blockIdx.x;
    int bid = (orig & 7) * 96 + (orig >> 3);   // same-n blocks -> same XCD
    int n = bid / 24;
    int o0 = (bid % 24) * 8;
    int tid = threadIdx.x, wid = tid >> 6, lane = tid & 63;
    int lr = lane & 15, lg = lane >> 4;
    int colt = wid & 1;
    int rt0 = (wid >> 1) * 13;                 // 26 row-tiles split 13/13

    // zero-init LDS once (finite-garbage safety for pad-k reads)
    for (int p = tid; p < 2 * BUF_B / 16; p += 256) ((u32x4*)x3Lb)[p] = u32x4{0,0,0,0};

    // GEMM1 B-frags: colt0 cols = (s0,o0..7)|(s1,o0..7); colt1 = (s2,o0..7)|(down,o0..7)
    const float* wsrc = (colt == 0)
        ? w3 + ((size_t)((lr >> 3) * O_ + o0 + (lr & 7))) * C_
        : ((lr < 8) ? w3 + ((size_t)(2 * O_ + o0 + lr)) * C_
                    : dw + ((size_t)(o0 + lr - 8)) * C_);
    bf16x8 bw[2];
    #pragma unroll
    for (int ks = 0; ks < 2; ++ks) {
        u16x8 tmp;
        #pragma unroll
        for (int j = 0; j < 8; ++j) {
            int c = ks * 32 + (lg << 2) + (j & 3) + ((j >> 2) << 4);
            tmp[j] = f2b(wsrc[c]);
        }
        bw[ks] = __builtin_bit_cast(bf16x8, tmp);
    }
    float dbv = (colt == 1 && lr >= 8) ? db[o0 + lr - 8] : 0.f;

    // per-lane LDS write column base
    int wo = (colt == 0) ? (lr & 7) : lr;
    int wsb = (colt == 0) ? (lr >> 3) : 2;
    int colbyte = wo * OSTR_B + wsb * SSTR_B;

    // hoisted GEMM2 B-frags + bias: wave covers o = o0 + wid*2 + {0,1}
    const bf16x8* a2v = (const bf16x8*)a2f;
    bf16x8 Bh[2][6];
    float rsb0[2], rsb1[2];
    #pragma unroll
    for (int oi = 0; oi < 2; ++oi) {
        int o = o0 + (wid << 1) + oi;
        const bf16x8* bp = a2v + ((size_t)(n * O_ + o)) * 6 * 64 + lane;
        #pragma unroll
        for (int q = 0; q < 6; ++q) Bh[oi][q] = bp[(size_t)q * 64];
        const float* rsp = rs_tot + ((size_t)(n * O_ + o)) * V_;
        rsb0[oi] = rsp[lr];
        rsb1[oi] = (lr < 9) ? rsp[16 + lr] : 0.f;
    }

    float sy1[2] = {0, 0}, sy2[2] = {0, 0};
    float sd1 = 0.f, sd2 = 0.f;
    const u16* xbn = xq + (size_t)n * TRP * 64;
    int rdw = 13 * lr + 2 * lg;                // GEMM2 read dword base within column
    __syncthreads();                           // init fence

    for (int ch = 0; ch < 16; ++ch) {
        int t0 = ch * 16;
        char* buf = x3Lb + (ch & 1) * BUF_B;
        const u16* xrow = xbn + (size_t)t0 * RP * 64;
        // ---- GEMM1: 2x b128 global loads, 2 MFMA, 1 b64 LDS write per row-tile
        for (int rt = rt0; rt < rt0 + 13; ++rt) {
            const u16* ap = xrow + (size_t)(rt * 16 + lr) * 64 + (lg << 4);
            u16x8 A0 = *(const u16x8*)ap;
            u16x8 A1 = *(const u16x8*)(ap + 8);
            f32x4 acc = {0.f, 0.f, 0.f, 0.f};
            acc = mfma16(__builtin_bit_cast(bf16x8, A0), bw[0], acc);
            acc = mfma16(__builtin_bit_cast(bf16x8, A1), bw[1], acc);
            int rbase = rt * 16 + (lg << 2);
            if (colt == 0 || lr < 8) {
                u16x4 w;
                #pragma unroll
                for (int reg = 0; reg < 4; ++reg) w[reg] = f2b(acc[reg]);
                *(u16x4*)(buf + colbyte + rbase * 2) = w;
            } else {
                size_t xdb = ((size_t)(n * O_ + o0 + lr - 8)) * TV + (size_t)t0 * V_;
                #pragma unroll
                for (int reg = 0; reg < 4; ++reg) {
                    int rr = rbase + reg;
                    int t = rr / RP, v = rr - t * RP;
                    if (v < 25) {
                        float val = acc[reg] + dbv;
                        xdws[xdb + t * V_ + v] = f2b(val);
                        sd1 += val; sd2 += val * val;
                    }
                }
            }
        }
        __syncthreads();   // handoff; double-buffer covers write-after-read
        // ---- GEMM2: y[t,u] = sum_{s,v} X3[t,(s,v)] * A2[(s,v),u]
        #pragma unroll
        for (int oi = 0; oi < 2; ++oi) {
            int ol = (wid << 1) + oi;
            int o = o0 + ol;
            const u32* L = (const u32*)(buf + ol * OSTR_B);
            f32x4 acc0 = {0, 0, 0, 0}, acc1 = {0, 0, 0, 0};
            #pragma unroll
            for (int s = 0; s < 3; ++s) {
                const u32* Ls = L + s * 208 + rdw;
                u32 d0 = Ls[0], d1 = Ls[1], d8 = Ls[8], d9 = Ls[9];
                bf16x8 A = __builtin_bit_cast(bf16x8, u32x4{d0, d1, d8, d9});
                acc0 = mfma16(A, Bh[oi][s * 2 + 0], acc0);
                acc1 = mfma16(A, Bh[oi][s * 2 + 1], acc1);
            }
            size_t yb = ((size_t)(n * O_ + o) * T_ + t0 + (lg << 2)) * V_;
            #pragma unroll
            for (int reg = 0; reg < 4; ++reg) {
                float v0 = acc0[reg] + rsb0[oi];
                yout[yb + (size_t)reg * V_ + lr] = v0;
                sy1[oi] += v0; sy2[oi] += v0 * v0;
                if (lr < 9) {
                    float v1 = acc1[reg] + rsb1[oi];
                    yout[yb + (size_t)reg * V_ + 16 + lr] = v1;
                    sy1[oi] += v1; sy2[oi] += v1 * v1;
                }
            }
        }
    }
    // stats -> global atomics
    #pragma unroll
    for (int oi = 0; oi < 2; ++oi) {
        float v1 = sy1[oi], v2 = sy2[oi];
        #pragma unroll
        for (int m = 1; m < 64; m <<= 1) {
            v1 += __shfl_xor(v1, m);
            v2 += __shfl_xor(v2, m);
        }
        if (lane == 0) {
            atomicAdd(&stats[0 * O_ + o0 + (wid << 1) + oi], v1);
            atomicAdd(&stats[1 * O_ + o0 + (wid << 1) + oi], v2);
        }
    }
    if (colt == 1) {
        float v1 = sd1, v2 = sd2;
        v1 += __shfl_xor(v1, 16); v2 += __shfl_xor(v2, 16);
        v1 += __shfl_xor(v1, 32); v2 += __shfl_xor(v2, 32);
        if (lane >= 8 && lane < 16) {
            atomicAdd(&stats[2 * O_ + o0 + lane - 8], v1);
            atomicAdd(&stats[3 * O_ + o0 + lane - 8], v2);
        }
    }
}

// ---------------- K4: BN coefficients ----------------
__global__ void k4_coef(const float* __restrict__ bn_w, const float* __restrict__ bn_b,
                        const float* __restrict__ dbn_w, const float* __restrict__ dbn_b,
                        const float* __restrict__ stats, float* __restrict__ coef) {
    int o = threadIdx.x;
    if (o >= O_) return;
    float inv = 1.f / (float)(N_ * T_ * V_);
    float mu_y = stats[o] * inv;
    float var_y = stats[O_ + o] * inv - mu_y * mu_y;
    float ay = bn_w[o] * rsqrtf(var_y + 1e-5f);
    float by = bn_b[o] - mu_y * ay;
    float mu_d = stats[2 * O_ + o] * inv;
    float var_d = stats[3 * O_ + o] * inv - mu_d * mu_d;
    float ad = dbn_w[o] * rsqrtf(var_d + 1e-5f);
    float bd = dbn_b[o] - mu_d * ad;
    coef[o] = ay; coef[O_ + o] = by; coef[2 * O_ + o] = ad; coef[3 * O_ + o] = bd;
}

// ---------------- K5: final BN+residual+relu (in-place on d_out) ----------------
__global__ void k5_final(float* __restrict__ out, const u16* __restrict__ xd,
                         const float* __restrict__ cf) {
    size_t total = (size_t)N_ * O_ * TV / 8;
    for (size_t i = blockIdx.x * (size_t)blockDim.x + threadIdx.x; i < total;
         i += (size_t)gridDim.x * blockDim.x) {
        int o = (int)((i / 800) % O_);
        float ay = cf[o], by = cf[O_ + o], ad = cf[2 * O_ + o], bd = cf[3 * O_ + o];
        float4 y0 = ((float4*)out)[2 * i];
        float4 y1 = ((float4*)out)[2 * i + 1];
        u16x8 dv = ((const u16x8*)xd)[i];
        float4 r0, r1;
        r0.x = fmaxf(ay * y0.x + by + ad * b2f(dv[0]) + bd, 0.f);
        r0.y = fmaxf(ay * y0.y + by + ad * b2f(dv[1]) + bd, 0.f);
        r0.z = fmaxf(ay * y0.z + by + ad * b2f(dv[2]) + bd, 0.f);
        r0.w = fmaxf(ay * y0.w + by + ad * b2f(dv[3]) + bd, 0.f);
        r1.x = fmaxf(ay * y1.x + by + ad * b2f(dv[4]) + bd, 0.f);
        r1.y = fmaxf(ay * y1.y + by + ad * b2f(dv[5]) + bd, 0.f);
        r1.z = fmaxf(ay * y1.z + by + ad * b2f(dv[6]) + bd, 0.f);
        r1.w = fmaxf(ay * y1.w + by + ad * b2f(dv[7]) + bd, 0.f);
        ((float4*)out)[2 * i] = r0;
        ((float4*)out)[2 * i + 1] = r1;
    }
}

extern "C" void kernel_launch(void* const* d_in, const int* in_sizes, int n_in,
                              void* d_out, int out_size, void* d_ws, size_t ws_size,
                              hipStream_t stream) {
    const float* x     = (const float*)d_in[0];
    const float* spd   = (const float*)d_in[1];
    const float* A3    = (const float*)d_in[2];
    const float* A6    = (const float*)d_in[3];
    const float* w1    = (const float*)d_in[4];
    const float* b1    = (const float*)d_in[5];
    const float* w2    = (const float*)d_in[6];
    const float* b2    = (const float*)d_in[7];
    const float* w4    = (const float*)d_in[8];
    const float* b4    = (const float*)d_in[9];
    const float* w3    = (const float*)d_in[10];
    const float* b3    = (const float*)d_in[11];
    const float* alpha = (const float*)d_in[12];
    const float* beta  = (const float*)d_in[13];
    const float* gamma = (const float*)d_in[14];
    const float* bn_w  = (const float*)d_in[15];
    const float* bn_b  = (const float*)d_in[16];
    const float* dw    = (const float*)d_in[17];
    const float* db    = (const float*)d_in[18];
    const float* dbn_w = (const float*)d_in[19];
    const float* dbn_b = (const float*)d_in[20];
    float* out = (float*)d_out;
    u16*   wsu = (u16*)d_ws;
    float* wsf = (float*)d_ws;

    u16* a2f  = wsu + WS_A2F_U;
    u16* xq   = wsu + WS_XQ_U;
    u16* xd   = wsu + WS_XD_U;
    float* xm    = wsf + WS_XM_F;
    float* rs    = wsf + WS_RS_F;
    float* stats = wsf + WS_STAT_F;
    float* coef  = wsf + WS_COEF_F;

    // zero rs_tot + stats (contiguous) — accumulated via atomics each call
    hipMemsetAsync(rs, 0, (N_ * O_ * V_ + 4 * O_) * sizeof(float), stream);

    k0_xq<<<N_ * 128, 256, 0, stream>>>(x, xq);
    k1_xm<<<N_ * C_, 256, 0, stream>>>(x, xm);
    k2_a2f<<<N_ * S_ * 8, 256, 0, stream>>>(spd, A3, A6, w1, b1, w2, b2, w4, b4, b3,
                                            alpha, beta, gamma, a2f, xm, rs);
    k3_main<<<N_ * 24, 256, 0, stream>>>(xq, w3, dw, db, a2f, rs, out, xd, stats);
    k4_coef<<<1, 256, 0, stream>>>(bn_w, bn_b, dbn_w, dbn_b, stats, coef);
    k5_final<<<4096, 256, 0, stream>>>(out, xd, coef);
}